// Round 9
// baseline (17168.732 us; speedup 1.0000x reference)
//
#include <hip/hip_runtime.h>
#include <math.h>

// ESBN: encoder (conv x3 + linear) + 64-step LSTM/memory scan. fp32.
// R9: persistent cooperative scan kernel, flag-synced via agent-scope atomics
// (no grid.sync -> no per-sync L2 flush). Cross-block data (X, Gp) moves
// through __hip_atomic_* AGENT loads/stores (coherence point). MkT and C are
// now block-private (LDS / registers). Encoder: R6 split (measured best).

__device__ __forceinline__ float sigm(float x) { return 1.0f / (1.0f + expf(-x)); }

#define ALOAD(p)    __hip_atomic_load((p), __ATOMIC_RELAXED, __HIP_MEMORY_SCOPE_AGENT)
#define ASTORE(p,v) __hip_atomic_store((p), (v), __ATOMIC_RELAXED, __HIP_MEMORY_SCOPE_AGENT)

// ---------------------------------------------------------------------------
// prep: transposed weights in ws.
//   WT [580][2048] (rows 0..64 w_ih^T, 65..576 w_hh^T, 577..579 zero),
//   bsum[2048], w1T[48][32], w2T[512][64], w3T[1024][64], ewT[256][64]
// ---------------------------------------------------------------------------
#define PREP_N (1187840 + 2048 + 1536 + 32768 + 65536 + 16384)
__global__ __launch_bounds__(256) void prep_kernel(
    const float* __restrict__ w_ih, const float* __restrict__ w_hh,
    const float* __restrict__ b_ih, const float* __restrict__ b_hh,
    const float* __restrict__ w1, const float* __restrict__ w2,
    const float* __restrict__ w3, const float* __restrict__ ew,
    float* __restrict__ WT, float* __restrict__ bsum,
    float* __restrict__ w1T, float* __restrict__ w2T,
    float* __restrict__ w3T, float* __restrict__ ewT)
{
  int i = blockIdx.x * 256 + threadIdx.x;
  if (i < 1187840) {
    const int r = i >> 11, c = i & 2047;
    float v;
    if (r < 65)       v = w_ih[(size_t)c * 65 + r];
    else if (r < 577) v = w_hh[(size_t)c * 512 + (r - 65)];
    else              v = 0.0f;
    WT[i] = v; return;
  }
  i -= 1187840;
  if (i < 2048) { bsum[i] = b_ih[i] + b_hh[i]; return; }
  i -= 2048;
  if (i < 1536) { const int r = i >> 5, oc = i & 31; w1T[i] = w1[oc * 48 + r]; return; }
  i -= 1536;
  if (i < 32768) { const int r = i >> 6, oc = i & 63; w2T[i] = w2[oc * 512 + r]; return; }
  i -= 32768;
  if (i < 65536) { const int r = i >> 6, oc = i & 63; w3T[i] = w3[oc * 1024 + r]; return; }
  i -= 65536;
  if (i < 16384) { const int k = i >> 6, d = i & 63; ewT[i] = ew[d * 256 + k]; return; }
}

// ---------------------------------------------------------------------------
// E1: conv1 (3->32, k4 s2, out 15x15, ReLU), one block per sample.
// ---------------------------------------------------------------------------
#define ENT 192
__global__ __launch_bounds__(ENT) void conv1_kernel(
    const float* __restrict__ images,
    const float* __restrict__ w1T, const float* __restrict__ b1,
    float* __restrict__ c1g, const int s0)
{
  __shared__ __align__(16) float buf[3072];
  const int bid = blockIdx.x;
  const int tid = threadIdx.x;
  {
    const float4* src = (const float4*)(images + (size_t)(s0 + bid) * 3072);
    float4* dst = (float4*)buf;
    for (int i = tid; i < 768; i += ENT) dst[i] = src[i];
  }
  __syncthreads();

  float* outp = c1g + (size_t)bid * 7680;
  for (int s = tid; s < 360; s += ENT) {
    const int ocg  = s & 7;
    const int pg   = s >> 3;
    const int row  = pg / 3;
    const int colg = pg - row * 3;
    const int ox0  = colg * 5;
    float acc[4][5];
    #pragma unroll
    for (int o = 0; o < 4; ++o) {
      const float bb = b1[ocg * 4 + o];
      #pragma unroll
      for (int p = 0; p < 5; ++p) acc[o][p] = bb;
    }
    #pragma unroll
    for (int ic = 0; ic < 3; ++ic) {
      #pragma unroll
      for (int ky = 0; ky < 4; ++ky) {
        const int y = 2 * row + ky;
        const float* ib = &buf[ic * 1024 + y * 32 + 2 * ox0];
        float v[12];
        #pragma unroll
        for (int i = 0; i < 6; ++i) { float2 t2 = *(const float2*)(ib + 2 * i); v[2*i] = t2.x; v[2*i+1] = t2.y; }
        float w_[4][4];
        #pragma unroll
        for (int kx = 0; kx < 4; ++kx)
          *(float4*)&w_[kx][0] = *(const float4*)(w1T + (ic * 16 + ky * 4 + kx) * 32 + ocg * 4);
        #pragma unroll
        for (int o = 0; o < 4; ++o)
          #pragma unroll
          for (int p = 0; p < 5; ++p)
            acc[o][p] += w_[0][o] * v[2*p] + w_[1][o] * v[2*p+1] + w_[2][o] * v[2*p+2] + w_[3][o] * v[2*p+3];
      }
    }
    #pragma unroll
    for (int o = 0; o < 4; ++o)
      #pragma unroll
      for (int p = 0; p < 5; ++p)
        outp[(ocg * 4 + o) * 240 + row * 16 + ox0 + p] = fmaxf(acc[o][p], 0.0f);
  }
}

// ---------------------------------------------------------------------------
// E2: conv2 + conv3 + linear, one block per sample.
// ---------------------------------------------------------------------------
__global__ __launch_bounds__(ENT) void enc2_kernel(
    const float* __restrict__ c1g,
    const float* __restrict__ w2T, const float* __restrict__ b2,
    const float* __restrict__ w3T, const float* __restrict__ b3,
    const float* __restrict__ ewT, const float* __restrict__ eb,
    float* __restrict__ z_all, const int s0)
{
  __shared__ __align__(16) float c1[7680];
  __shared__ __align__(16) float buf[2368];
  const int bid = blockIdx.x;
  const int tid = threadIdx.x;

  {
    const float4* src = (const float4*)(c1g + (size_t)bid * 7680);
    float4* dst = (float4*)c1;
    for (int i = tid; i < 1920; i += ENT) dst[i] = src[i];
  }
  __syncthreads();

  {
    const int ocg = tid & 15;
    const int pg  = tid >> 4;
    const int row = pg >> 1;
    const int ox0 = (pg & 1) * 3;
    float acc[4][3];
    #pragma unroll
    for (int o = 0; o < 4; ++o) {
      const float bb = b2[ocg * 4 + o];
      acc[o][0] = bb; acc[o][1] = bb; acc[o][2] = bb;
    }
    for (int ic = 0; ic < 32; ++ic) {
      #pragma unroll
      for (int ky = 0; ky < 4; ++ky) {
        const int y = 2 * row + ky;
        const float* ib = &c1[ic * 240 + y * 16 + 2 * ox0];
        float v[8];
        #pragma unroll
        for (int i = 0; i < 4; ++i) { float2 t2 = *(const float2*)(ib + 2 * i); v[2*i] = t2.x; v[2*i+1] = t2.y; }
        float w_[4][4];
        #pragma unroll
        for (int kx = 0; kx < 4; ++kx)
          *(float4*)&w_[kx][0] = *(const float4*)(w2T + (ic * 16 + ky * 4 + kx) * 64 + ocg * 4);
        #pragma unroll
        for (int o = 0; o < 4; ++o)
          #pragma unroll
          for (int p = 0; p < 3; ++p)
            acc[o][p] += w_[0][o] * v[2*p] + w_[1][o] * v[2*p+1] + w_[2][o] * v[2*p+2] + w_[3][o] * v[2*p+3];
      }
    }
    #pragma unroll
    for (int o = 0; o < 4; ++o)
      #pragma unroll
      for (int p = 0; p < 3; ++p)
        buf[(ocg * 4 + o) * 37 + row * 6 + ox0 + p] = fmaxf(acc[o][p], 0.0f);
  }
  __syncthreads();

  {
    const int oc = tid & 63;
    const int kc = tid >> 6;
    const int k0 = (kc * 256) / 3, k1 = ((kc + 1) * 256) / 3;
    float acc[4] = {0.f, 0.f, 0.f, 0.f};
    for (int it = k0; it < k1; ++it) {
      const int ic = it >> 2;
      const int ky = it & 3;
      float v[2][6];
      #pragma unroll
      for (int oy = 0; oy < 2; ++oy) {
        const float* ib = &buf[ic * 37 + (2 * oy + ky) * 6];
        #pragma unroll
        for (int i = 0; i < 3; ++i) { float2 t2 = *(const float2*)(ib + 2 * i); v[oy][2*i] = t2.x; v[oy][2*i+1] = t2.y; }
      }
      float w_[4];
      #pragma unroll
      for (int kx = 0; kx < 4; ++kx) w_[kx] = w3T[(ic * 16 + ky * 4 + kx) * 64 + oc];
      #pragma unroll
      for (int p = 0; p < 4; ++p) {
        const int oy = p >> 1, ox = p & 1;
        acc[p] += w_[0] * v[oy][2*ox] + w_[1] * v[oy][2*ox+1] + w_[2] * v[oy][2*ox+2] + w_[3] * v[oy][2*ox+3];
      }
    }
    #pragma unroll
    for (int p = 0; p < 4; ++p) c1[kc * 260 + p * 64 + oc] = acc[p];
  }
  __syncthreads();

  for (int o = tid; o < 256; o += ENT) {
    const int oc = o >> 2, p = o & 3;
    c1[1024 + o] = b3[oc] + c1[p * 64 + oc] + c1[260 + p * 64 + oc] + c1[520 + p * 64 + oc];
  }
  __syncthreads();

  {
    const int d  = tid & 63;
    const int kc = tid >> 6;
    const int k0 = (kc * 256) / 3, k1 = ((kc + 1) * 256) / 3;
    float s = 0.0f;
    for (int k = k0; k < k1; ++k) s += ewT[k * 64 + d] * c1[1024 + k];
    c1[1536 + kc * 64 + d] = s;
  }
  __syncthreads();
  if (tid < 64) {
    z_all[(size_t)(s0 + bid) * 64 + tid] = eb[tid] + c1[1536 + tid] + c1[1600 + tid] + c1[1664 + tid];
  }
}

// ---------------------------------------------------------------------------
// Monolithic encoder fallback (if ws can't hold c1g chunks).
// ---------------------------------------------------------------------------
__global__ __launch_bounds__(ENT) void encoder_kernel(
    const float* __restrict__ images,
    const float* __restrict__ w1T, const float* __restrict__ b1,
    const float* __restrict__ w2T, const float* __restrict__ b2,
    const float* __restrict__ w3T, const float* __restrict__ b3,
    const float* __restrict__ ewT, const float* __restrict__ eb,
    float* __restrict__ z_all)
{
  __shared__ __align__(16) float c1[7744];
  __shared__ __align__(16) float buf[3072];
  const int bid = blockIdx.x;
  const int tid = threadIdx.x;
  {
    const float4* src = (const float4*)(images + (size_t)bid * 3072);
    float4* dst = (float4*)buf;
    for (int i = tid; i < 768; i += ENT) dst[i] = src[i];
  }
  __syncthreads();
  for (int s = tid; s < 360; s += ENT) {
    const int ocg  = s & 7;
    const int pg   = s >> 3;
    const int row  = pg / 3;
    const int colg = pg - row * 3;
    const int ox0  = colg * 5;
    float acc[4][5];
    #pragma unroll
    for (int o = 0; o < 4; ++o) {
      const float bb = b1[ocg * 4 + o];
      #pragma unroll
      for (int p = 0; p < 5; ++p) acc[o][p] = bb;
    }
    #pragma unroll
    for (int ic = 0; ic < 3; ++ic) {
      #pragma unroll
      for (int ky = 0; ky < 4; ++ky) {
        const int y = 2 * row + ky;
        const float* ib = &buf[ic * 1024 + y * 32 + 2 * ox0];
        float v[12];
        #pragma unroll
        for (int i = 0; i < 6; ++i) { float2 t2 = *(const float2*)(ib + 2 * i); v[2*i] = t2.x; v[2*i+1] = t2.y; }
        float w_[4][4];
        #pragma unroll
        for (int kx = 0; kx < 4; ++kx)
          *(float4*)&w_[kx][0] = *(const float4*)(w1T + (ic * 16 + ky * 4 + kx) * 32 + ocg * 4);
        #pragma unroll
        for (int o = 0; o < 4; ++o)
          #pragma unroll
          for (int p = 0; p < 5; ++p)
            acc[o][p] += w_[0][o] * v[2*p] + w_[1][o] * v[2*p+1] + w_[2][o] * v[2*p+2] + w_[3][o] * v[2*p+3];
      }
    }
    #pragma unroll
    for (int o = 0; o < 4; ++o)
      #pragma unroll
      for (int p = 0; p < 5; ++p)
        c1[(ocg * 4 + o) * 242 + row * 16 + ox0 + p] = fmaxf(acc[o][p], 0.0f);
  }
  __syncthreads();
  {
    const int ocg = tid & 15;
    const int pg  = tid >> 4;
    const int row = pg >> 1;
    const int ox0 = (pg & 1) * 3;
    float acc[4][3];
    #pragma unroll
    for (int o = 0; o < 4; ++o) {
      const float bb = b2[ocg * 4 + o];
      acc[o][0] = bb; acc[o][1] = bb; acc[o][2] = bb;
    }
    for (int ic = 0; ic < 32; ++ic) {
      #pragma unroll
      for (int ky = 0; ky < 4; ++ky) {
        const int y = 2 * row + ky;
        const float* ib = &c1[ic * 242 + y * 16 + 2 * ox0];
        float v[8];
        #pragma unroll
        for (int i = 0; i < 4; ++i) { float2 t2 = *(const float2*)(ib + 2 * i); v[2*i] = t2.x; v[2*i+1] = t2.y; }
        float w_[4][4];
        #pragma unroll
        for (int kx = 0; kx < 4; ++kx)
          *(float4*)&w_[kx][0] = *(const float4*)(w2T + (ic * 16 + ky * 4 + kx) * 64 + ocg * 4);
        #pragma unroll
        for (int o = 0; o < 4; ++o)
          #pragma unroll
          for (int p = 0; p < 3; ++p)
            acc[o][p] += w_[0][o] * v[2*p] + w_[1][o] * v[2*p+1] + w_[2][o] * v[2*p+2] + w_[3][o] * v[2*p+3];
      }
    }
    __syncthreads();
    #pragma unroll
    for (int o = 0; o < 4; ++o)
      #pragma unroll
      for (int p = 0; p < 3; ++p)
        buf[(ocg * 4 + o) * 38 + row * 6 + ox0 + p] = fmaxf(acc[o][p], 0.0f);
  }
  __syncthreads();
  {
    const int oc = tid & 63;
    const int kc = tid >> 6;
    const int k0 = (kc * 256) / 3, k1 = ((kc + 1) * 256) / 3;
    float acc[4] = {0.f, 0.f, 0.f, 0.f};
    for (int it = k0; it < k1; ++it) {
      const int ic = it >> 2;
      const int ky = it & 3;
      float v[2][6];
      #pragma unroll
      for (int oy = 0; oy < 2; ++oy) {
        const float* ib = &buf[ic * 38 + (2 * oy + ky) * 6];
        #pragma unroll
        for (int i = 0; i < 3; ++i) { float2 t2 = *(const float2*)(ib + 2 * i); v[oy][2*i] = t2.x; v[oy][2*i+1] = t2.y; }
      }
      float w_[4];
      #pragma unroll
      for (int kx = 0; kx < 4; ++kx) w_[kx] = w3T[(ic * 16 + ky * 4 + kx) * 64 + oc];
      #pragma unroll
      for (int p = 0; p < 4; ++p) {
        const int oy = p >> 1, ox = p & 1;
        acc[p] += w_[0] * v[oy][2*ox] + w_[1] * v[oy][2*ox+1] + w_[2] * v[oy][2*ox+2] + w_[3] * v[oy][2*ox+3];
      }
    }
    #pragma unroll
    for (int p = 0; p < 4; ++p) c1[kc * 260 + p * 64 + oc] = acc[p];
  }
  __syncthreads();
  for (int o = tid; o < 256; o += ENT) {
    const int oc = o >> 2, p = o & 3;
    c1[1024 + o] = b3[oc] + c1[p * 64 + oc] + c1[260 + p * 64 + oc] + c1[520 + p * 64 + oc];
  }
  __syncthreads();
  {
    const int d  = tid & 63;
    const int kc = tid >> 6;
    const int k0 = (kc * 256) / 3, k1 = ((kc + 1) * 256) / 3;
    float s = 0.0f;
    for (int k = k0; k < k1; ++k) s += ewT[k * 64 + d] * c1[1024 + k];
    c1[1536 + kc * 64 + d] = s;
  }
  __syncthreads();
  if (tid < 64) {
    z_all[(size_t)bid * 64 + tid] = eb[tid] + c1[1536 + tid] + c1[1600 + tid] + c1[1664 + tid];
  }
}

// ---------------------------------------------------------------------------
// z-Gram: z_gram[b][t][n] = z_t . z_n
// ---------------------------------------------------------------------------
__global__ __launch_bounds__(256) void gram_kernel(
    const float* __restrict__ z_all, float* __restrict__ z_gram)
{
  const int b = blockIdx.x;
  const int tid = threadIdx.x;
  __shared__ float zsb[64 * 65];
  for (int i = tid; i < 4096; i += 256) {
    const int tt = i >> 6, d = i & 63;
    zsb[tt * 65 + d] = z_all[((size_t)tt * 256 + b) * 64 + d];
  }
  __syncthreads();
  const int n = tid & 63, tg = tid >> 6;
  for (int tt = tg; tt < 64; tt += 4) {
    float s = 0.0f;
    #pragma unroll
    for (int d = 0; d < 64; ++d) s += zsb[tt * 65 + d] * zsb[n * 65 + d];
    z_gram[((size_t)b * 64 + tt) * 64 + n] = s;
  }
}

// ---------------------------------------------------------------------------
// Persistent scan: 512 blocks x 256 thr, 2 blocks/CU, cooperative launch for
// co-residency ONLY (no grid.sync). Flag sync via agent-scope atomics.
// Per step t:
//   all blocks: wait x_ctr>=256*t; stage X[b0..b0+16][577] to LDS; gates GEMM
//   (bt=bid>>5, jt=bid&31 -> 64-j slice; jt == bid mod 32 pins W slice to one
//   XCD L2); atomic-store Gp slice; bump g_ctr (release).
//   blocks<256 (b=bid): wait g_ctr>=512*(t+1); LSTM elementwise (C in regs),
//   h -> LDS + X; 69 dots (kw -> LDS MkT, y -> out, g); softmax from z_gram;
//   memory read from LDS MkT -> kx -> X; bump x_ctr (release).
// ---------------------------------------------------------------------------
__global__ __launch_bounds__(256, 2) void scan_persist_kernel(
    const float* __restrict__ WT, const float* __restrict__ bsum,
    const float* __restrict__ z_gram,
    float* X, float* Gp, unsigned int* ctrs, float* o_ptr,
    const float* __restrict__ out_w, const float* __restrict__ out_b,
    const float* __restrict__ gate_w, const float* __restrict__ gate_b,
    const float* __restrict__ key_w, const float* __restrict__ key_b,
    const float* __restrict__ conf_w, const float* __restrict__ conf_b)
{
  __shared__ __align__(16) float Xs[16 * 584];   // [b][k], row pad to 584
  __shared__ __align__(16) float mk[64 * 65];    // MkT_b: [d][n], stride 65
  __shared__ __align__(16) float hs[512];
  __shared__ __align__(16) float wks[64];
  __shared__ float sgv, kxp;

  const int tid = threadIdx.x;
  const int bid = blockIdx.x;
  const int jt  = bid & 31, bt = bid >> 5;
  const int b0  = bt * 16;
  const int tj  = tid & 15, tb = tid >> 4;
  const int j0  = jt * 64 + tj * 4;
  unsigned int* gc = ctrs;
  unsigned int* xc = ctrs + 16;

  for (int i = tid; i < 64 * 65; i += 256) mk[i] = 0.0f;
  float cr0 = 0.0f, cr1 = 0.0f;
  const float cw = conf_w[0], cb = conf_b[0];

  for (int t = 0; t < 64; ++t) {
    // ---- wait X(t) ready (t=0: memset zeros, trivially ready)
    if (t > 0) {
      if (tid == 0) {
        while ((int)__hip_atomic_load(xc, __ATOMIC_ACQUIRE, __HIP_MEMORY_SCOPE_AGENT) < 256 * t) {}
      }
    }
    __syncthreads();

    // ---- stage X slice [b0..b0+16][0..577] -> Xs[bl][k]
    for (int i = tid; i < 16 * 577; i += 256) {
      const int bl = i / 577, k = i - bl * 577;
      Xs[bl * 584 + k] = ALOAD(X + (size_t)(b0 + bl) * 577 + k);
    }
    __syncthreads();

    // ---- gates GEMM: thread = 1b(tb) x 4j(tj*4) over k=0..576
    {
      float a0 = 0.f, a1 = 0.f, a2 = 0.f, a3 = 0.f;
      const float* wp = WT + j0;
      const float* xp = Xs + tb * 584;
      #pragma unroll 2
      for (int k = 0; k < 576; k += 4) {
        const float4 x4 = *(const float4*)(xp + k);
        const float xv[4] = {x4.x, x4.y, x4.z, x4.w};
        #pragma unroll
        for (int kk = 0; kk < 4; ++kk) {
          const float4 w = *(const float4*)(wp + (size_t)(k + kk) * 2048);
          a0 += xv[kk] * w.x; a1 += xv[kk] * w.y; a2 += xv[kk] * w.z; a3 += xv[kk] * w.w;
        }
      }
      { // k = 576
        const float x = xp[576];
        const float4 w = *(const float4*)(wp + (size_t)576 * 2048);
        a0 += x * w.x; a1 += x * w.y; a2 += x * w.z; a3 += x * w.w;
      }
      float* gp = Gp + (size_t)(b0 + tb) * 2048 + j0;
      ASTORE(gp + 0, a0); ASTORE(gp + 1, a1); ASTORE(gp + 2, a2); ASTORE(gp + 3, a3);
    }
    __syncthreads();   // all threads' Gp stores drained (vmcnt0) before bump
    if (tid == 0) __hip_atomic_fetch_add(gc, 1u, __ATOMIC_RELEASE, __HIP_MEMORY_SCOPE_AGENT);

    // ---- step phase: one block per batch element
    if (bid < 256) {
      const int b = bid;
      if (tid == 0) {
        while ((int)__hip_atomic_load(gc, __ATOMIC_ACQUIRE, __HIP_MEMORY_SCOPE_AGENT) < 512 * (t + 1)) {}
      }
      __syncthreads();

      // LSTM elementwise: jj = tid, tid+256 (C in registers cr0/cr1)
      {
        float* gp = Gp + (size_t)b * 2048;
        {
          const int jj = tid;
          const float gi = bsum[jj]        + ALOAD(gp + jj);
          const float gf = bsum[512 + jj]  + ALOAD(gp + 512 + jj);
          const float gg = bsum[1024 + jj] + ALOAD(gp + 1024 + jj);
          const float go = bsum[1536 + jj] + ALOAD(gp + 1536 + jj);
          const float c2 = sigm(gf) * cr0 + sigm(gi) * tanhf(gg);
          cr0 = c2;
          const float h = sigm(go) * tanhf(c2);
          hs[jj] = h;
          ASTORE(X + (size_t)b * 577 + 65 + jj, h);
        }
        {
          const int jj = tid + 256;
          const float gi = bsum[jj]        + ALOAD(gp + jj);
          const float gf = bsum[512 + jj]  + ALOAD(gp + 512 + jj);
          const float gg = bsum[1024 + jj] + ALOAD(gp + 1024 + jj);
          const float go = bsum[1536 + jj] + ALOAD(gp + 1536 + jj);
          const float c2 = sigm(gf) * cr1 + sigm(gi) * tanhf(gg);
          cr1 = c2;
          const float h = sigm(go) * tanhf(c2);
          hs[jj] = h;
          ASTORE(X + (size_t)b * 577 + 65 + jj, h);
        }
      }
      __syncthreads();

      // 69 dots: kw[0..63] -> mk col t, y[64..67] -> out, g[68] -> sgv
      {
        const int lane = tid & 63, wid = tid >> 6;
        for (int d = wid; d < 69; d += 4) {
          const float* row = (d < 64) ? (key_w + (size_t)d * 512)
                           : (d < 68) ? (out_w + (size_t)(d - 64) * 512)
                                      : gate_w;
          float a = 0.0f;
          #pragma unroll
          for (int kk = 0; kk < 8; ++kk) a += hs[lane + kk * 64] * row[lane + kk * 64];
          #pragma unroll
          for (int m = 32; m > 0; m >>= 1) a += __shfl_xor(a, m);
          if (lane == 0) {
            if (d < 64)      mk[d * 65 + t] = a + key_b[d];
            else if (d < 68) o_ptr[(size_t)t * 1024 + b * 4 + (d - 64)] = a + out_b[d - 64];
            else             sgv = sigm(a + gate_b[0]);
          }
        }
      }
      __syncthreads();

      if (t == 0) {
        if (tid < 65) ASTORE(X + (size_t)b * 577 + tid, 0.0f);
      } else {
        if (tid < 64) {
          const int n = tid;
          const float sim = z_gram[((size_t)b * 64 + t) * 64 + n];
          const bool valid = (n < t);
          float mx = valid ? sim : -3.0e38f;
          #pragma unroll
          for (int m = 32; m > 0; m >>= 1) mx = fmaxf(mx, __shfl_xor(mx, m));
          const float p = valid ? expf(sim - mx) : 0.0f;
          float sum = p;
          #pragma unroll
          for (int m = 32; m > 0; m >>= 1) sum += __shfl_xor(sum, m);
          const float wk = p / sum;
          wks[n] = wk;
          float kc = wk * sigm(sim * cw + cb);
          #pragma unroll
          for (int m = 32; m > 0; m >>= 1) kc += __shfl_xor(kc, m);
          if (n == 0) kxp = kc;
        }
        __syncthreads();
        if (tid < 64) {
          const int d = tid;
          float a = 0.0f;
          #pragma unroll
          for (int n = 0; n < 64; ++n) a += mk[d * 65 + n] * wks[n];
          ASTORE(X + (size_t)b * 577 + d, sgv * a);
          if (tid == 0) ASTORE(X + (size_t)b * 577 + 64, sgv * kxp);
        }
      }
      __syncthreads();   // all X stores drained before bump
      if (tid == 0) __hip_atomic_fetch_add(xc, 1u, __ATOMIC_RELEASE, __HIP_MEMORY_SCOPE_AGENT);
    }
  }
}

// ---------------------------------------------------------------------------
extern "C" void kernel_launch(void* const* d_in, const int* in_sizes, int n_in,
                              void* d_out, int out_size, void* d_ws, size_t ws_size,
                              hipStream_t stream) {
  const float* images = (const float*)d_in[0];
  const float* w1     = (const float*)d_in[1];
  const float* b1     = (const float*)d_in[2];
  const float* w2     = (const float*)d_in[3];
  const float* b2     = (const float*)d_in[4];
  const float* w3     = (const float*)d_in[5];
  const float* b3     = (const float*)d_in[6];
  const float* ew     = (const float*)d_in[7];
  const float* eb     = (const float*)d_in[8];
  const float* w_ih   = (const float*)d_in[9];
  const float* w_hh   = (const float*)d_in[10];
  const float* b_ih   = (const float*)d_in[11];
  const float* b_hh   = (const float*)d_in[12];
  const float* out_w  = (const float*)d_in[13];
  const float* out_b  = (const float*)d_in[14];
  const float* gate_w = (const float*)d_in[15];
  const float* gate_b = (const float*)d_in[16];
  const float* key_w  = (const float*)d_in[17];
  const float* key_b  = (const float*)d_in[18];
  const float* conf_w = (const float*)d_in[19];
  const float* conf_b = (const float*)d_in[20];
  float* o_ptr = (float*)d_out;
  float* ws    = (float*)d_ws;

  // ws layout (floats)
  float* WT     = ws;                  // [0, 1187840)
  float* bsum   = ws + 1187840;        // 2048
  float* w1T    = ws + 1189888;        // 1536
  float* w2T    = ws + 1191424;        // 32768
  float* w3T    = ws + 1224192;        // 65536
  float* ewT    = ws + 1289728;        // 16384
  float* z_all  = ws + 1306112;        // 1,048,576
  float* z_gram = ws + 2354688;        // 1,048,576
  float* X      = ws + 3403264;        // 256*577 = 147,712
  float* Gp     = ws + 3550976;        // 256*2048 = 524,288
  unsigned int* ctrs = (unsigned int*)(ws + 4075264);   // 64 ints
  const size_t baseF = 4075392;
  float* c1g = ws + baseF;
  const size_t availF = (ws_size / 4 > baseF) ? (ws_size / 4 - baseF) : 0;
  long chunkL = (long)(availF / 7680ull);
  int chunk = (chunkL > 16384) ? 16384 : (int)chunkL;

  hipMemsetAsync(X,    0, 147712 * sizeof(float), stream);
  hipMemsetAsync(ctrs, 0, 64 * sizeof(unsigned int), stream);

  prep_kernel<<<(PREP_N + 255) / 256, 256, 0, stream>>>(
      w_ih, w_hh, b_ih, b_hh, w1, w2, w3, ew, WT, bsum, w1T, w2T, w3T, ewT);

  if (chunk >= 2048) {
    for (int s0 = 0; s0 < 16384; s0 += chunk) {
      const int n = (16384 - s0 < chunk) ? (16384 - s0) : chunk;
      conv1_kernel<<<n, ENT, 0, stream>>>(images, w1T, b1, c1g, s0);
      enc2_kernel<<<n, ENT, 0, stream>>>(c1g, w2T, b2, w3T, b3, ewT, eb, z_all, s0);
    }
  } else {
    encoder_kernel<<<16384, ENT, 0, stream>>>(images, w1T, b1, w2T, b2, w3T, b3, ewT, eb, z_all);
  }

  gram_kernel<<<256, 256, 0, stream>>>(z_all, z_gram);

  void* args[] = { (void*)&WT, (void*)&bsum, (void*)&z_gram,
                   (void*)&X, (void*)&Gp, (void*)&ctrs, (void*)&o_ptr,
                   (void*)&out_w, (void*)&out_b, (void*)&gate_w, (void*)&gate_b,
                   (void*)&key_w, (void*)&key_b, (void*)&conf_w, (void*)&conf_b };
  hipLaunchCooperativeKernel((void*)scan_persist_kernel, dim3(512), dim3(256),
                             args, 0, stream);
}

// Round 10
// 5729.205 us; speedup vs baseline: 2.9967x; 2.9967x over previous
//
#include <hip/hip_runtime.h>
#include <math.h>

// ESBN: encoder (conv x3 + linear) + 64-step LSTM/memory scan. fp32.
// R10: single-launch persistent scan; per-block tagged flags (plain relaxed
// agent stores, one cacheline each, <=16 pollers) + one agent acquire/release
// fence per phase; all data via normal vectorized ld/st. Exploits that the
// 256 batch sequences are independent: block bid = gates(bt,jt) + step(b=bid).
// Encoder: R6 split (measured best).

__device__ __forceinline__ float sigm(float x) { return 1.0f / (1.0f + expf(-x)); }

__device__ __forceinline__ unsigned int flagLoad(const unsigned int* p) {
  return __hip_atomic_load(p, __ATOMIC_RELAXED, __HIP_MEMORY_SCOPE_AGENT);
}
__device__ __forceinline__ void flagStore(unsigned int* p, unsigned int v) {
  __hip_atomic_store(p, v, __ATOMIC_RELAXED, __HIP_MEMORY_SCOPE_AGENT);
}

// ---------------------------------------------------------------------------
// prep: transposed weights in ws.
//   WT [580][2048] (rows 0..64 w_ih^T, 65..576 w_hh^T, 577..579 zero),
//   bsum[2048], w1T[48][32], w2T[512][64], w3T[1024][64], ewT[256][64]
// ---------------------------------------------------------------------------
#define PREP_N (1187840 + 2048 + 1536 + 32768 + 65536 + 16384)
__global__ __launch_bounds__(256) void prep_kernel(
    const float* __restrict__ w_ih, const float* __restrict__ w_hh,
    const float* __restrict__ b_ih, const float* __restrict__ b_hh,
    const float* __restrict__ w1, const float* __restrict__ w2,
    const float* __restrict__ w3, const float* __restrict__ ew,
    float* __restrict__ WT, float* __restrict__ bsum,
    float* __restrict__ w1T, float* __restrict__ w2T,
    float* __restrict__ w3T, float* __restrict__ ewT)
{
  int i = blockIdx.x * 256 + threadIdx.x;
  if (i < 1187840) {
    const int r = i >> 11, c = i & 2047;
    float v;
    if (r < 65)       v = w_ih[(size_t)c * 65 + r];
    else if (r < 577) v = w_hh[(size_t)c * 512 + (r - 65)];
    else              v = 0.0f;
    WT[i] = v; return;
  }
  i -= 1187840;
  if (i < 2048) { bsum[i] = b_ih[i] + b_hh[i]; return; }
  i -= 2048;
  if (i < 1536) { const int r = i >> 5, oc = i & 31; w1T[i] = w1[oc * 48 + r]; return; }
  i -= 1536;
  if (i < 32768) { const int r = i >> 6, oc = i & 63; w2T[i] = w2[oc * 512 + r]; return; }
  i -= 32768;
  if (i < 65536) { const int r = i >> 6, oc = i & 63; w3T[i] = w3[oc * 1024 + r]; return; }
  i -= 65536;
  if (i < 16384) { const int k = i >> 6, d = i & 63; ewT[i] = ew[d * 256 + k]; return; }
}

// ---------------------------------------------------------------------------
// E1: conv1 (3->32, k4 s2, out 15x15, ReLU), one block per sample.
// ---------------------------------------------------------------------------
#define ENT 192
__global__ __launch_bounds__(ENT) void conv1_kernel(
    const float* __restrict__ images,
    const float* __restrict__ w1T, const float* __restrict__ b1,
    float* __restrict__ c1g, const int s0)
{
  __shared__ __align__(16) float buf[3072];
  const int bid = blockIdx.x;
  const int tid = threadIdx.x;
  {
    const float4* src = (const float4*)(images + (size_t)(s0 + bid) * 3072);
    float4* dst = (float4*)buf;
    for (int i = tid; i < 768; i += ENT) dst[i] = src[i];
  }
  __syncthreads();

  float* outp = c1g + (size_t)bid * 7680;
  for (int s = tid; s < 360; s += ENT) {
    const int ocg  = s & 7;
    const int pg   = s >> 3;
    const int row  = pg / 3;
    const int colg = pg - row * 3;
    const int ox0  = colg * 5;
    float acc[4][5];
    #pragma unroll
    for (int o = 0; o < 4; ++o) {
      const float bb = b1[ocg * 4 + o];
      #pragma unroll
      for (int p = 0; p < 5; ++p) acc[o][p] = bb;
    }
    #pragma unroll
    for (int ic = 0; ic < 3; ++ic) {
      #pragma unroll
      for (int ky = 0; ky < 4; ++ky) {
        const int y = 2 * row + ky;
        const float* ib = &buf[ic * 1024 + y * 32 + 2 * ox0];
        float v[12];
        #pragma unroll
        for (int i = 0; i < 6; ++i) { float2 t2 = *(const float2*)(ib + 2 * i); v[2*i] = t2.x; v[2*i+1] = t2.y; }
        float w_[4][4];
        #pragma unroll
        for (int kx = 0; kx < 4; ++kx)
          *(float4*)&w_[kx][0] = *(const float4*)(w1T + (ic * 16 + ky * 4 + kx) * 32 + ocg * 4);
        #pragma unroll
        for (int o = 0; o < 4; ++o)
          #pragma unroll
          for (int p = 0; p < 5; ++p)
            acc[o][p] += w_[0][o] * v[2*p] + w_[1][o] * v[2*p+1] + w_[2][o] * v[2*p+2] + w_[3][o] * v[2*p+3];
      }
    }
    #pragma unroll
    for (int o = 0; o < 4; ++o)
      #pragma unroll
      for (int p = 0; p < 5; ++p)
        outp[(ocg * 4 + o) * 240 + row * 16 + ox0 + p] = fmaxf(acc[o][p], 0.0f);
  }
}

// ---------------------------------------------------------------------------
// E2: conv2 + conv3 + linear, one block per sample.
// ---------------------------------------------------------------------------
__global__ __launch_bounds__(ENT) void enc2_kernel(
    const float* __restrict__ c1g,
    const float* __restrict__ w2T, const float* __restrict__ b2,
    const float* __restrict__ w3T, const float* __restrict__ b3,
    const float* __restrict__ ewT, const float* __restrict__ eb,
    float* __restrict__ z_all, const int s0)
{
  __shared__ __align__(16) float c1[7680];
  __shared__ __align__(16) float buf[2368];
  const int bid = blockIdx.x;
  const int tid = threadIdx.x;

  {
    const float4* src = (const float4*)(c1g + (size_t)bid * 7680);
    float4* dst = (float4*)c1;
    for (int i = tid; i < 1920; i += ENT) dst[i] = src[i];
  }
  __syncthreads();

  {
    const int ocg = tid & 15;
    const int pg  = tid >> 4;
    const int row = pg >> 1;
    const int ox0 = (pg & 1) * 3;
    float acc[4][3];
    #pragma unroll
    for (int o = 0; o < 4; ++o) {
      const float bb = b2[ocg * 4 + o];
      acc[o][0] = bb; acc[o][1] = bb; acc[o][2] = bb;
    }
    for (int ic = 0; ic < 32; ++ic) {
      #pragma unroll
      for (int ky = 0; ky < 4; ++ky) {
        const int y = 2 * row + ky;
        const float* ib = &c1[ic * 240 + y * 16 + 2 * ox0];
        float v[8];
        #pragma unroll
        for (int i = 0; i < 4; ++i) { float2 t2 = *(const float2*)(ib + 2 * i); v[2*i] = t2.x; v[2*i+1] = t2.y; }
        float w_[4][4];
        #pragma unroll
        for (int kx = 0; kx < 4; ++kx)
          *(float4*)&w_[kx][0] = *(const float4*)(w2T + (ic * 16 + ky * 4 + kx) * 64 + ocg * 4);
        #pragma unroll
        for (int o = 0; o < 4; ++o)
          #pragma unroll
          for (int p = 0; p < 3; ++p)
            acc[o][p] += w_[0][o] * v[2*p] + w_[1][o] * v[2*p+1] + w_[2][o] * v[2*p+2] + w_[3][o] * v[2*p+3];
      }
    }
    #pragma unroll
    for (int o = 0; o < 4; ++o)
      #pragma unroll
      for (int p = 0; p < 3; ++p)
        buf[(ocg * 4 + o) * 37 + row * 6 + ox0 + p] = fmaxf(acc[o][p], 0.0f);
  }
  __syncthreads();

  {
    const int oc = tid & 63;
    const int kc = tid >> 6;
    const int k0 = (kc * 256) / 3, k1 = ((kc + 1) * 256) / 3;
    float acc[4] = {0.f, 0.f, 0.f, 0.f};
    for (int it = k0; it < k1; ++it) {
      const int ic = it >> 2;
      const int ky = it & 3;
      float v[2][6];
      #pragma unroll
      for (int oy = 0; oy < 2; ++oy) {
        const float* ib = &buf[ic * 37 + (2 * oy + ky) * 6];
        #pragma unroll
        for (int i = 0; i < 3; ++i) { float2 t2 = *(const float2*)(ib + 2 * i); v[oy][2*i] = t2.x; v[oy][2*i+1] = t2.y; }
      }
      float w_[4];
      #pragma unroll
      for (int kx = 0; kx < 4; ++kx) w_[kx] = w3T[(ic * 16 + ky * 4 + kx) * 64 + oc];
      #pragma unroll
      for (int p = 0; p < 4; ++p) {
        const int oy = p >> 1, ox = p & 1;
        acc[p] += w_[0] * v[oy][2*ox] + w_[1] * v[oy][2*ox+1] + w_[2] * v[oy][2*ox+2] + w_[3] * v[oy][2*ox+3];
      }
    }
    #pragma unroll
    for (int p = 0; p < 4; ++p) c1[kc * 260 + p * 64 + oc] = acc[p];
  }
  __syncthreads();

  for (int o = tid; o < 256; o += ENT) {
    const int oc = o >> 2, p = o & 3;
    c1[1024 + o] = b3[oc] + c1[p * 64 + oc] + c1[260 + p * 64 + oc] + c1[520 + p * 64 + oc];
  }
  __syncthreads();

  {
    const int d  = tid & 63;
    const int kc = tid >> 6;
    const int k0 = (kc * 256) / 3, k1 = ((kc + 1) * 256) / 3;
    float s = 0.0f;
    for (int k = k0; k < k1; ++k) s += ewT[k * 64 + d] * c1[1024 + k];
    c1[1536 + kc * 64 + d] = s;
  }
  __syncthreads();
  if (tid < 64) {
    z_all[(size_t)(s0 + bid) * 64 + tid] = eb[tid] + c1[1536 + tid] + c1[1600 + tid] + c1[1664 + tid];
  }
}

// ---------------------------------------------------------------------------
// Monolithic encoder fallback (if ws can't hold c1g chunks).
// ---------------------------------------------------------------------------
__global__ __launch_bounds__(ENT) void encoder_kernel(
    const float* __restrict__ images,
    const float* __restrict__ w1T, const float* __restrict__ b1,
    const float* __restrict__ w2T, const float* __restrict__ b2,
    const float* __restrict__ w3T, const float* __restrict__ b3,
    const float* __restrict__ ewT, const float* __restrict__ eb,
    float* __restrict__ z_all)
{
  __shared__ __align__(16) float c1[7744];
  __shared__ __align__(16) float buf[3072];
  const int bid = blockIdx.x;
  const int tid = threadIdx.x;
  {
    const float4* src = (const float4*)(images + (size_t)bid * 3072);
    float4* dst = (float4*)buf;
    for (int i = tid; i < 768; i += ENT) dst[i] = src[i];
  }
  __syncthreads();
  for (int s = tid; s < 360; s += ENT) {
    const int ocg  = s & 7;
    const int pg   = s >> 3;
    const int row  = pg / 3;
    const int colg = pg - row * 3;
    const int ox0  = colg * 5;
    float acc[4][5];
    #pragma unroll
    for (int o = 0; o < 4; ++o) {
      const float bb = b1[ocg * 4 + o];
      #pragma unroll
      for (int p = 0; p < 5; ++p) acc[o][p] = bb;
    }
    #pragma unroll
    for (int ic = 0; ic < 3; ++ic) {
      #pragma unroll
      for (int ky = 0; ky < 4; ++ky) {
        const int y = 2 * row + ky;
        const float* ib = &buf[ic * 1024 + y * 32 + 2 * ox0];
        float v[12];
        #pragma unroll
        for (int i = 0; i < 6; ++i) { float2 t2 = *(const float2*)(ib + 2 * i); v[2*i] = t2.x; v[2*i+1] = t2.y; }
        float w_[4][4];
        #pragma unroll
        for (int kx = 0; kx < 4; ++kx)
          *(float4*)&w_[kx][0] = *(const float4*)(w1T + (ic * 16 + ky * 4 + kx) * 32 + ocg * 4);
        #pragma unroll
        for (int o = 0; o < 4; ++o)
          #pragma unroll
          for (int p = 0; p < 5; ++p)
            acc[o][p] += w_[0][o] * v[2*p] + w_[1][o] * v[2*p+1] + w_[2][o] * v[2*p+2] + w_[3][o] * v[2*p+3];
      }
    }
    #pragma unroll
    for (int o = 0; o < 4; ++o)
      #pragma unroll
      for (int p = 0; p < 5; ++p)
        c1[(ocg * 4 + o) * 242 + row * 16 + ox0 + p] = fmaxf(acc[o][p], 0.0f);
  }
  __syncthreads();
  {
    const int ocg = tid & 15;
    const int pg  = tid >> 4;
    const int row = pg >> 1;
    const int ox0 = (pg & 1) * 3;
    float acc[4][3];
    #pragma unroll
    for (int o = 0; o < 4; ++o) {
      const float bb = b2[ocg * 4 + o];
      acc[o][0] = bb; acc[o][1] = bb; acc[o][2] = bb;
    }
    for (int ic = 0; ic < 32; ++ic) {
      #pragma unroll
      for (int ky = 0; ky < 4; ++ky) {
        const int y = 2 * row + ky;
        const float* ib = &c1[ic * 242 + y * 16 + 2 * ox0];
        float v[8];
        #pragma unroll
        for (int i = 0; i < 4; ++i) { float2 t2 = *(const float2*)(ib + 2 * i); v[2*i] = t2.x; v[2*i+1] = t2.y; }
        float w_[4][4];
        #pragma unroll
        for (int kx = 0; kx < 4; ++kx)
          *(float4*)&w_[kx][0] = *(const float4*)(w2T + (ic * 16 + ky * 4 + kx) * 64 + ocg * 4);
        #pragma unroll
        for (int o = 0; o < 4; ++o)
          #pragma unroll
          for (int p = 0; p < 3; ++p)
            acc[o][p] += w_[0][o] * v[2*p] + w_[1][o] * v[2*p+1] + w_[2][o] * v[2*p+2] + w_[3][o] * v[2*p+3];
      }
    }
    __syncthreads();
    #pragma unroll
    for (int o = 0; o < 4; ++o)
      #pragma unroll
      for (int p = 0; p < 3; ++p)
        buf[(ocg * 4 + o) * 38 + row * 6 + ox0 + p] = fmaxf(acc[o][p], 0.0f);
  }
  __syncthreads();
  {
    const int oc = tid & 63;
    const int kc = tid >> 6;
    const int k0 = (kc * 256) / 3, k1 = ((kc + 1) * 256) / 3;
    float acc[4] = {0.f, 0.f, 0.f, 0.f};
    for (int it = k0; it < k1; ++it) {
      const int ic = it >> 2;
      const int ky = it & 3;
      float v[2][6];
      #pragma unroll
      for (int oy = 0; oy < 2; ++oy) {
        const float* ib = &buf[ic * 38 + (2 * oy + ky) * 6];
        #pragma unroll
        for (int i = 0; i < 3; ++i) { float2 t2 = *(const float2*)(ib + 2 * i); v[oy][2*i] = t2.x; v[oy][2*i+1] = t2.y; }
      }
      float w_[4];
      #pragma unroll
      for (int kx = 0; kx < 4; ++kx) w_[kx] = w3T[(ic * 16 + ky * 4 + kx) * 64 + oc];
      #pragma unroll
      for (int p = 0; p < 4; ++p) {
        const int oy = p >> 1, ox = p & 1;
        acc[p] += w_[0] * v[oy][2*ox] + w_[1] * v[oy][2*ox+1] + w_[2] * v[oy][2*ox+2] + w_[3] * v[oy][2*ox+3];
      }
    }
    #pragma unroll
    for (int p = 0; p < 4; ++p) c1[kc * 260 + p * 64 + oc] = acc[p];
  }
  __syncthreads();
  for (int o = tid; o < 256; o += ENT) {
    const int oc = o >> 2, p = o & 3;
    c1[1024 + o] = b3[oc] + c1[p * 64 + oc] + c1[260 + p * 64 + oc] + c1[520 + p * 64 + oc];
  }
  __syncthreads();
  {
    const int d  = tid & 63;
    const int kc = tid >> 6;
    const int k0 = (kc * 256) / 3, k1 = ((kc + 1) * 256) / 3;
    float s = 0.0f;
    for (int k = k0; k < k1; ++k) s += ewT[k * 64 + d] * c1[1024 + k];
    c1[1536 + kc * 64 + d] = s;
  }
  __syncthreads();
  if (tid < 64) {
    z_all[(size_t)bid * 64 + tid] = eb[tid] + c1[1536 + tid] + c1[1600 + tid] + c1[1664 + tid];
  }
}

// ---------------------------------------------------------------------------
// z-Gram: z_gram[b][t][n] = z_t . z_n
// ---------------------------------------------------------------------------
__global__ __launch_bounds__(256) void gram_kernel(
    const float* __restrict__ z_all, float* __restrict__ z_gram)
{
  const int b = blockIdx.x;
  const int tid = threadIdx.x;
  __shared__ float zsb[64 * 65];
  for (int i = tid; i < 4096; i += 256) {
    const int tt = i >> 6, d = i & 63;
    zsb[tt * 65 + d] = z_all[((size_t)tt * 256 + b) * 64 + d];
  }
  __syncthreads();
  const int n = tid & 63, tg = tid >> 6;
  for (int tt = tg; tt < 64; tt += 4) {
    float s = 0.0f;
    #pragma unroll
    for (int d = 0; d < 64; ++d) s += zsb[tt * 65 + d] * zsb[n * 65 + d];
    z_gram[((size_t)b * 64 + tt) * 64 + n] = s;
  }
}

// ---------------------------------------------------------------------------
// Persistent single-launch scan. 256 blocks x 512 thr (1/CU, cooperative).
// Block bid: gates for (bt=bid>>4 -> b0..b0+16, j in [jt*128, jt*128+128))
// AND step-owner of batch b=bid. Per step:
//   gates: poll xflag[b0..b0+16] >= t (relaxed), acquire-fence, stage X to
//          LDS, GEMV, store Gp slice, release-fence, gflag[bid] = t+1.
//   step:  poll gflag of 16 sibling blocks >= t+1, acquire-fence, LSTM
//          elementwise (C in reg, MkT in LDS), dots, softmax, memory read,
//          write X[b], release-fence, xflag[bid] = t+1.
// Flags: one per block, 64B apart, plain tagged stores (no RMW).
// ---------------------------------------------------------------------------
__global__ __launch_bounds__(512, 1) void scan_onekernel(
    const float* __restrict__ WT, const float* __restrict__ bsum,
    const float* __restrict__ z_gram,
    float* __restrict__ X, float* __restrict__ Gp,
    unsigned int* xflag, unsigned int* gflag, float* __restrict__ o_ptr,
    const float* __restrict__ out_w, const float* __restrict__ out_b,
    const float* __restrict__ gate_w, const float* __restrict__ gate_b,
    const float* __restrict__ key_w, const float* __restrict__ key_b,
    const float* __restrict__ conf_w, const float* __restrict__ conf_b)
{
  __shared__ __align__(16) float Xs[16 * 584];   // staged X slice [b][k]
  __shared__ __align__(16) float mk[64 * 65];    // MkT for batch b (private)
  __shared__ __align__(16) float hs[512];
  __shared__ __align__(16) float wks[64];
  __shared__ float sgv_s, kxp_s;

  const int tid = threadIdx.x;
  const int bid = blockIdx.x;        // 0..255; owns batch b = bid
  const int bt  = bid >> 4;
  const int jt  = bid & 15;
  const int b0  = bt * 16;
  const int b   = bid;
  const int tj  = tid & 31, tb = tid >> 5;   // gemv: 32 j-lanes x 16 b-groups
  const int j0  = jt * 128 + tj * 4;

  for (int i = tid; i < 64 * 65; i += 512) mk[i] = 0.0f;
  float creg = 0.0f;                 // C[b][tid]
  const float cw = conf_w[0], cb = conf_b[0];

  for (int t = 0; t < 64; ++t) {
    // ===== gates role: Gp[b0..b0+16][j0..j0+128) = X(t) @ WT slice =====
    if (t > 0) {
      if (tid < 16) {
        while (flagLoad(xflag + (b0 + tid) * 16) < (unsigned)t) {}
      }
      if (tid < 64) __builtin_amdgcn_fence(__ATOMIC_ACQUIRE, "agent");
    }
    __syncthreads();

    for (int i = tid; i < 16 * 580; i += 512) {
      const int bl = i / 580, k = i - bl * 580;
      Xs[bl * 584 + k] = (k < 577) ? X[(size_t)(b0 + bl) * 577 + k] : 0.0f;
    }
    __syncthreads();

    {
      float a0 = 0.f, a1 = 0.f, a2 = 0.f, a3 = 0.f;
      const float* wp = WT + j0;
      const float* xp = Xs + tb * 584;
      #pragma unroll 4
      for (int k = 0; k < 580; k += 4) {
        const float4 x4 = *(const float4*)(xp + k);
        const float xv[4] = {x4.x, x4.y, x4.z, x4.w};
        #pragma unroll
        for (int kk = 0; kk < 4; ++kk) {
          const float4 w = *(const float4*)(wp + (size_t)(k + kk) * 2048);
          a0 += xv[kk] * w.x; a1 += xv[kk] * w.y;
          a2 += xv[kk] * w.z; a3 += xv[kk] * w.w;
        }
      }
      float4 r; r.x = a0; r.y = a1; r.z = a2; r.w = a3;
      *(float4*)(Gp + (size_t)(b0 + tb) * 2048 + j0) = r;
    }
    __syncthreads();   // all waves' Gp stores drained (barrier implies vmcnt0)
    if (tid == 0) {
      __builtin_amdgcn_fence(__ATOMIC_RELEASE, "agent");
      flagStore(gflag + bid * 16, (unsigned)(t + 1));
    }

    // ===== step role for batch b =====
    if (tid < 16) {
      while (flagLoad(gflag + (bt * 16 + tid) * 16) < (unsigned)(t + 1)) {}
    }
    if (tid < 64) __builtin_amdgcn_fence(__ATOMIC_ACQUIRE, "agent");
    __syncthreads();

    {   // LSTM elementwise: thread owns j = tid; C in register
      const int j = tid;
      const float* gp = Gp + (size_t)b * 2048;
      const float gi = bsum[j]        + gp[j];
      const float gf = bsum[512 + j]  + gp[512 + j];
      const float gg = bsum[1024 + j] + gp[1024 + j];
      const float go = bsum[1536 + j] + gp[1536 + j];
      const float c2 = sigm(gf) * creg + sigm(gi) * tanhf(gg);
      creg = c2;
      const float h = sigm(go) * tanhf(c2);
      hs[j] = h;
      X[(size_t)b * 577 + 65 + j] = h;
    }
    __syncthreads();

    {   // 69 dots: kw -> mk col t, y -> out, g -> sgv
      const int lane = tid & 63, wid = tid >> 6;
      for (int d = wid; d < 69; d += 8) {
        const float* row = (d < 64) ? (key_w + (size_t)d * 512)
                         : (d < 68) ? (out_w + (size_t)(d - 64) * 512)
                                    : gate_w;
        float a = 0.0f;
        #pragma unroll
        for (int kk = 0; kk < 8; ++kk) a += hs[lane + kk * 64] * row[lane + kk * 64];
        #pragma unroll
        for (int m = 32; m > 0; m >>= 1) a += __shfl_xor(a, m);
        if (lane == 0) {
          if (d < 64)      mk[d * 65 + t] = a + key_b[d];
          else if (d < 68) o_ptr[(size_t)t * 1024 + b * 4 + (d - 64)] = a + out_b[d - 64];
          else             sgv_s = sigm(a + gate_b[0]);
        }
      }
    }
    __syncthreads();

    if (t == 0) {
      if (tid < 65) X[(size_t)b * 577 + tid] = 0.0f;
    } else {
      if (tid < 64) {   // masked softmax + ck reduce (wave 0)
        const int n = tid;
        const float sim = z_gram[((size_t)b * 64 + t) * 64 + n];
        const bool valid = (n < t);
        float mx = valid ? sim : -3.0e38f;
        #pragma unroll
        for (int m = 32; m > 0; m >>= 1) mx = fmaxf(mx, __shfl_xor(mx, m));
        const float p = valid ? expf(sim - mx) : 0.0f;
        float sum = p;
        #pragma unroll
        for (int m = 32; m > 0; m >>= 1) sum += __shfl_xor(sum, m);
        const float wk = p / sum;
        wks[n] = wk;
        float kc = wk * sigm(sim * cw + cb);
        #pragma unroll
        for (int m = 32; m > 0; m >>= 1) kc += __shfl_xor(kc, m);
        if (n == 0) kxp_s = kc;
      }
      __syncthreads();
      if (tid < 64) {   // kx[d] = sg * sum_n wk[n] * mk[d][n]
        const int d = tid;
        float a = 0.0f;
        #pragma unroll 8
        for (int n = 0; n < 64; ++n) a += mk[d * 65 + n] * wks[n];
        X[(size_t)b * 577 + d] = sgv_s * a;
      } else if (tid == 64) {
        X[(size_t)b * 577 + 64] = sgv_s * kxp_s;
      }
    }
    __syncthreads();   // all X stores drained
    if (tid == 0) {
      __builtin_amdgcn_fence(__ATOMIC_RELEASE, "agent");
      flagStore(xflag + bid * 16, (unsigned)(t + 1));
    }
  }
}

// ---------------------------------------------------------------------------
extern "C" void kernel_launch(void* const* d_in, const int* in_sizes, int n_in,
                              void* d_out, int out_size, void* d_ws, size_t ws_size,
                              hipStream_t stream) {
  const float* images = (const float*)d_in[0];
  const float* w1     = (const float*)d_in[1];
  const float* b1     = (const float*)d_in[2];
  const float* w2     = (const float*)d_in[3];
  const float* b2     = (const float*)d_in[4];
  const float* w3     = (const float*)d_in[5];
  const float* b3     = (const float*)d_in[6];
  const float* ew     = (const float*)d_in[7];
  const float* eb     = (const float*)d_in[8];
  const float* w_ih   = (const float*)d_in[9];
  const float* w_hh   = (const float*)d_in[10];
  const float* b_ih   = (const float*)d_in[11];
  const float* b_hh   = (const float*)d_in[12];
  const float* out_w  = (const float*)d_in[13];
  const float* out_b  = (const float*)d_in[14];
  const float* gate_w = (const float*)d_in[15];
  const float* gate_b = (const float*)d_in[16];
  const float* key_w  = (const float*)d_in[17];
  const float* key_b  = (const float*)d_in[18];
  const float* conf_w = (const float*)d_in[19];
  const float* conf_b = (const float*)d_in[20];
  float* o_ptr = (float*)d_out;
  float* ws    = (float*)d_ws;

  // ws layout (floats)
  float* WT     = ws;                  // 1,187,840
  float* bsum   = ws + 1187840;        // 2,048
  float* w1T    = ws + 1189888;        // 1,536
  float* w2T    = ws + 1191424;        // 32,768
  float* w3T    = ws + 1224192;        // 65,536
  float* ewT    = ws + 1289728;        // 16,384
  float* z_all  = ws + 1306112;        // 1,048,576
  float* z_gram = ws + 2354688;        // 1,048,576
  float* X      = ws + 3403264;        // 147,712
  float* Gp     = ws + 3550976;        // 524,288
  unsigned int* xflag = (unsigned int*)(ws + 4075264);   // 256*16 uints
  unsigned int* gflag = (unsigned int*)(ws + 4079360);   // 256*16 uints
  const size_t baseF = 4083456;
  float* c1g = ws + baseF;
  const size_t availF = (ws_size / 4 > baseF) ? (ws_size / 4 - baseF) : 0;
  long chunkL = (long)(availF / 7680ull);
  int chunk = (chunkL > 16384) ? 16384 : (int)chunkL;

  hipMemsetAsync(X,     0, 147712 * sizeof(float), stream);
  hipMemsetAsync(xflag, 0, 8192 * sizeof(unsigned int), stream);   // x+g flags

  prep_kernel<<<(PREP_N + 255) / 256, 256, 0, stream>>>(
      w_ih, w_hh, b_ih, b_hh, w1, w2, w3, ew, WT, bsum, w1T, w2T, w3T, ewT);

  if (chunk >= 2048) {
    for (int s0 = 0; s0 < 16384; s0 += chunk) {
      const int n = (16384 - s0 < chunk) ? (16384 - s0) : chunk;
      conv1_kernel<<<n, ENT, 0, stream>>>(images, w1T, b1, c1g, s0);
      enc2_kernel<<<n, ENT, 0, stream>>>(c1g, w2T, b2, w3T, b3, ewT, eb, z_all, s0);
    }
  } else {
    encoder_kernel<<<16384, ENT, 0, stream>>>(images, w1T, b1, w2T, b2, w3T, b3, ewT, eb, z_all);
  }

  gram_kernel<<<256, 256, 0, stream>>>(z_all, z_gram);

  void* args[] = { (void*)&WT, (void*)&bsum, (void*)&z_gram,
                   (void*)&X, (void*)&Gp, (void*)&xflag, (void*)&gflag,
                   (void*)&o_ptr,
                   (void*)&out_w, (void*)&out_b, (void*)&gate_w, (void*)&gate_b,
                   (void*)&key_w, (void*)&key_b, (void*)&conf_w, (void*)&conf_b };
  hipLaunchCooperativeKernel((void*)scan_onekernel, dim3(256), dim3(512),
                             args, 0, stream);
}

// Round 11
// 5264.307 us; speedup vs baseline: 3.2613x; 1.0883x over previous
//
#include <hip/hip_runtime.h>
#include <math.h>

// ESBN: encoder (conv x3 + linear) + 64-step LSTM/memory scan. fp32.
// R11: (1) scan = 64 launches of ONE merged kernel: blocks 0-255 gates
// (no wait; W slice pinned to XCD bid%8), blocks 256-511 step (poll tagged
// flags + one acquire fence). Deadlock-free: producers never wait.
// (2) enc2 loads c1 in two halves -> LDS 24.8 KB -> 6 blocks/CU.

__device__ __forceinline__ float sigm(float x) { return 1.0f / (1.0f + expf(-x)); }

__device__ __forceinline__ unsigned int flagLoad(const unsigned int* p) {
  return __hip_atomic_load(p, __ATOMIC_RELAXED, __HIP_MEMORY_SCOPE_AGENT);
}
__device__ __forceinline__ void flagStore(unsigned int* p, unsigned int v) {
  __hip_atomic_store(p, v, __ATOMIC_RELAXED, __HIP_MEMORY_SCOPE_AGENT);
}

// ---------------------------------------------------------------------------
// prep: transposed weights in ws.
//   WT [580][2048] (rows 0..64 w_ih^T, 65..576 w_hh^T, 577..579 zero),
//   bsum[2048], w1T[48][32], w2T[512][64], w3T[1024][64], ewT[256][64]
// ---------------------------------------------------------------------------
#define PREP_N (1187840 + 2048 + 1536 + 32768 + 65536 + 16384)
__global__ __launch_bounds__(256) void prep_kernel(
    const float* __restrict__ w_ih, const float* __restrict__ w_hh,
    const float* __restrict__ b_ih, const float* __restrict__ b_hh,
    const float* __restrict__ w1, const float* __restrict__ w2,
    const float* __restrict__ w3, const float* __restrict__ ew,
    float* __restrict__ WT, float* __restrict__ bsum,
    float* __restrict__ w1T, float* __restrict__ w2T,
    float* __restrict__ w3T, float* __restrict__ ewT)
{
  int i = blockIdx.x * 256 + threadIdx.x;
  if (i < 1187840) {
    const int r = i >> 11, c = i & 2047;
    float v;
    if (r < 65)       v = w_ih[(size_t)c * 65 + r];
    else if (r < 577) v = w_hh[(size_t)c * 512 + (r - 65)];
    else              v = 0.0f;
    WT[i] = v; return;
  }
  i -= 1187840;
  if (i < 2048) { bsum[i] = b_ih[i] + b_hh[i]; return; }
  i -= 2048;
  if (i < 1536) { const int r = i >> 5, oc = i & 31; w1T[i] = w1[oc * 48 + r]; return; }
  i -= 1536;
  if (i < 32768) { const int r = i >> 6, oc = i & 63; w2T[i] = w2[oc * 512 + r]; return; }
  i -= 32768;
  if (i < 65536) { const int r = i >> 6, oc = i & 63; w3T[i] = w3[oc * 1024 + r]; return; }
  i -= 65536;
  if (i < 16384) { const int k = i >> 6, d = i & 63; ewT[i] = ew[d * 256 + k]; return; }
}

// ---------------------------------------------------------------------------
// E1: conv1 (3->32, k4 s2, out 15x15, ReLU), one block per sample.
// LDS = image only (12 KB). Output c1g[bid][32][240] (row stride 16).
// ---------------------------------------------------------------------------
#define ENT 192
__global__ __launch_bounds__(ENT) void conv1_kernel(
    const float* __restrict__ images,
    const float* __restrict__ w1T, const float* __restrict__ b1,
    float* __restrict__ c1g, const int s0)
{
  __shared__ __align__(16) float buf[3072];
  const int bid = blockIdx.x;
  const int tid = threadIdx.x;
  {
    const float4* src = (const float4*)(images + (size_t)(s0 + bid) * 3072);
    float4* dst = (float4*)buf;
    for (int i = tid; i < 768; i += ENT) dst[i] = src[i];
  }
  __syncthreads();

  float* outp = c1g + (size_t)bid * 7680;
  for (int s = tid; s < 360; s += ENT) {
    const int ocg  = s & 7;
    const int pg   = s >> 3;
    const int row  = pg / 3;
    const int colg = pg - row * 3;
    const int ox0  = colg * 5;
    float acc[4][5];
    #pragma unroll
    for (int o = 0; o < 4; ++o) {
      const float bb = b1[ocg * 4 + o];
      #pragma unroll
      for (int p = 0; p < 5; ++p) acc[o][p] = bb;
    }
    #pragma unroll
    for (int ic = 0; ic < 3; ++ic) {
      #pragma unroll
      for (int ky = 0; ky < 4; ++ky) {
        const int y = 2 * row + ky;
        const float* ib = &buf[ic * 1024 + y * 32 + 2 * ox0];
        float v[12];
        #pragma unroll
        for (int i = 0; i < 6; ++i) { float2 t2 = *(const float2*)(ib + 2 * i); v[2*i] = t2.x; v[2*i+1] = t2.y; }
        float w_[4][4];
        #pragma unroll
        for (int kx = 0; kx < 4; ++kx)
          *(float4*)&w_[kx][0] = *(const float4*)(w1T + (ic * 16 + ky * 4 + kx) * 32 + ocg * 4);
        #pragma unroll
        for (int o = 0; o < 4; ++o)
          #pragma unroll
          for (int p = 0; p < 5; ++p)
            acc[o][p] += w_[0][o] * v[2*p] + w_[1][o] * v[2*p+1] + w_[2][o] * v[2*p+2] + w_[3][o] * v[2*p+3];
      }
    }
    #pragma unroll
    for (int o = 0; o < 4; ++o)
      #pragma unroll
      for (int p = 0; p < 5; ++p)
        outp[(ocg * 4 + o) * 240 + row * 16 + ox0 + p] = fmaxf(acc[o][p], 0.0f);
  }
}

// ---------------------------------------------------------------------------
// E2 v2: conv2 + conv3 + linear; c1 loaded in TWO 16-ic halves.
// LDS: c1h [16][240] (15 KB) + c2 [64][37] (9.25 KB) = 24.8 KB -> 6 blk/CU.
// conv2 accumulates across halves in registers (no recompute).
// ---------------------------------------------------------------------------
__global__ __launch_bounds__(ENT) void enc2_kernel(
    const float* __restrict__ c1g,
    const float* __restrict__ w2T, const float* __restrict__ b2,
    const float* __restrict__ w3T, const float* __restrict__ b3,
    const float* __restrict__ ewT, const float* __restrict__ eb,
    float* __restrict__ z_all, const int s0)
{
  __shared__ __align__(16) float c1h[3840];   // [16][240]
  __shared__ __align__(16) float buf[2368];   // [64][37]
  const int bid = blockIdx.x;
  const int tid = threadIdx.x;

  // conv2 mapping: 4oc x 3pos, 192 slots exact
  const int ocg = tid & 15;
  const int pg  = tid >> 4;
  const int row = pg >> 1;
  const int ox0 = (pg & 1) * 3;
  float acc2[4][3];
  #pragma unroll
  for (int o = 0; o < 4; ++o) {
    const float bb = b2[ocg * 4 + o];
    acc2[o][0] = bb; acc2[o][1] = bb; acc2[o][2] = bb;
  }

  for (int half = 0; half < 2; ++half) {
    {
      const float4* src = (const float4*)(c1g + (size_t)bid * 7680 + half * 3840);
      float4* dst = (float4*)c1h;
      for (int i = tid; i < 960; i += ENT) dst[i] = src[i];
    }
    __syncthreads();
    for (int icl = 0; icl < 16; ++icl) {
      #pragma unroll
      for (int ky = 0; ky < 4; ++ky) {
        const int y = 2 * row + ky;
        const float* ib = &c1h[icl * 240 + y * 16 + 2 * ox0];
        float v[8];
        #pragma unroll
        for (int i = 0; i < 4; ++i) { float2 t2 = *(const float2*)(ib + 2 * i); v[2*i] = t2.x; v[2*i+1] = t2.y; }
        float w_[4][4];
        #pragma unroll
        for (int kx = 0; kx < 4; ++kx)
          *(float4*)&w_[kx][0] = *(const float4*)(w2T + ((half * 16 + icl) * 16 + ky * 4 + kx) * 64 + ocg * 4);
        #pragma unroll
        for (int o = 0; o < 4; ++o)
          #pragma unroll
          for (int p = 0; p < 3; ++p)
            acc2[o][p] += w_[0][o] * v[2*p] + w_[1][o] * v[2*p+1] + w_[2][o] * v[2*p+2] + w_[3][o] * v[2*p+3];
      }
    }
    __syncthreads();   // c1h reads done before next half's load (or conv3 writes)
  }

  // c2 -> buf
  #pragma unroll
  for (int o = 0; o < 4; ++o)
    #pragma unroll
    for (int p = 0; p < 3; ++p)
      buf[(ocg * 4 + o) * 37 + row * 6 + ox0 + p] = fmaxf(acc2[o][p], 0.0f);
  __syncthreads();

  // conv3: 64->64, k4 s2, out 2x2, NO ReLU. thread = oc(64) x kc(3).
  {
    const int oc = tid & 63;
    const int kc = tid >> 6;
    const int k0 = (kc * 256) / 3, k1 = ((kc + 1) * 256) / 3;
    float acc[4] = {0.f, 0.f, 0.f, 0.f};
    for (int it = k0; it < k1; ++it) {
      const int ic = it >> 2;
      const int ky = it & 3;
      float v[2][6];
      #pragma unroll
      for (int oy = 0; oy < 2; ++oy) {
        const float* ib = &buf[ic * 37 + (2 * oy + ky) * 6];
        #pragma unroll
        for (int i = 0; i < 3; ++i) { float2 t2 = *(const float2*)(ib + 2 * i); v[oy][2*i] = t2.x; v[oy][2*i+1] = t2.y; }
      }
      float w_[4];
      #pragma unroll
      for (int kx = 0; kx < 4; ++kx) w_[kx] = w3T[(ic * 16 + ky * 4 + kx) * 64 + oc];
      #pragma unroll
      for (int p = 0; p < 4; ++p) {
        const int oy = p >> 1, ox = p & 1;
        acc[p] += w_[0] * v[oy][2*ox] + w_[1] * v[oy][2*ox+1] + w_[2] * v[oy][2*ox+2] + w_[3] * v[oy][2*ox+3];
      }
    }
    #pragma unroll
    for (int p = 0; p < 4; ++p) c1h[kc * 260 + p * 64 + oc] = acc[p];   // psum [0,780)
  }
  __syncthreads();

  for (int o = tid; o < 256; o += ENT) {
    const int oc = o >> 2, p = o & 3;
    c1h[1024 + o] = b3[oc] + c1h[p * 64 + oc] + c1h[260 + p * 64 + oc] + c1h[520 + p * 64 + oc];
  }
  __syncthreads();

  {
    const int d  = tid & 63;
    const int kc = tid >> 6;
    const int k0 = (kc * 256) / 3, k1 = ((kc + 1) * 256) / 3;
    float s = 0.0f;
    for (int k = k0; k < k1; ++k) s += ewT[k * 64 + d] * c1h[1024 + k];
    c1h[1536 + kc * 64 + d] = s;
  }
  __syncthreads();
  if (tid < 64) {
    z_all[(size_t)(s0 + bid) * 64 + tid] = eb[tid] + c1h[1536 + tid] + c1h[1600 + tid] + c1h[1664 + tid];
  }
}

// ---------------------------------------------------------------------------
// Monolithic encoder fallback (if ws can't hold c1g chunks).
// ---------------------------------------------------------------------------
__global__ __launch_bounds__(ENT) void encoder_kernel(
    const float* __restrict__ images,
    const float* __restrict__ w1T, const float* __restrict__ b1,
    const float* __restrict__ w2T, const float* __restrict__ b2,
    const float* __restrict__ w3T, const float* __restrict__ b3,
    const float* __restrict__ ewT, const float* __restrict__ eb,
    float* __restrict__ z_all)
{
  __shared__ __align__(16) float c1[7744];
  __shared__ __align__(16) float buf[3072];
  const int bid = blockIdx.x;
  const int tid = threadIdx.x;
  {
    const float4* src = (const float4*)(images + (size_t)bid * 3072);
    float4* dst = (float4*)buf;
    for (int i = tid; i < 768; i += ENT) dst[i] = src[i];
  }
  __syncthreads();
  for (int s = tid; s < 360; s += ENT) {
    const int ocg  = s & 7;
    const int pg   = s >> 3;
    const int row  = pg / 3;
    const int colg = pg - row * 3;
    const int ox0  = colg * 5;
    float acc[4][5];
    #pragma unroll
    for (int o = 0; o < 4; ++o) {
      const float bb = b1[ocg * 4 + o];
      #pragma unroll
      for (int p = 0; p < 5; ++p) acc[o][p] = bb;
    }
    #pragma unroll
    for (int ic = 0; ic < 3; ++ic) {
      #pragma unroll
      for (int ky = 0; ky < 4; ++ky) {
        const int y = 2 * row + ky;
        const float* ib = &buf[ic * 1024 + y * 32 + 2 * ox0];
        float v[12];
        #pragma unroll
        for (int i = 0; i < 6; ++i) { float2 t2 = *(const float2*)(ib + 2 * i); v[2*i] = t2.x; v[2*i+1] = t2.y; }
        float w_[4][4];
        #pragma unroll
        for (int kx = 0; kx < 4; ++kx)
          *(float4*)&w_[kx][0] = *(const float4*)(w1T + (ic * 16 + ky * 4 + kx) * 32 + ocg * 4);
        #pragma unroll
        for (int o = 0; o < 4; ++o)
          #pragma unroll
          for (int p = 0; p < 5; ++p)
            acc[o][p] += w_[0][o] * v[2*p] + w_[1][o] * v[2*p+1] + w_[2][o] * v[2*p+2] + w_[3][o] * v[2*p+3];
      }
    }
    #pragma unroll
    for (int o = 0; o < 4; ++o)
      #pragma unroll
      for (int p = 0; p < 5; ++p)
        c1[(ocg * 4 + o) * 242 + row * 16 + ox0 + p] = fmaxf(acc[o][p], 0.0f);
  }
  __syncthreads();
  {
    const int ocg = tid & 15;
    const int pg  = tid >> 4;
    const int row = pg >> 1;
    const int ox0 = (pg & 1) * 3;
    float acc[4][3];
    #pragma unroll
    for (int o = 0; o < 4; ++o) {
      const float bb = b2[ocg * 4 + o];
      acc[o][0] = bb; acc[o][1] = bb; acc[o][2] = bb;
    }
    for (int ic = 0; ic < 32; ++ic) {
      #pragma unroll
      for (int ky = 0; ky < 4; ++ky) {
        const int y = 2 * row + ky;
        const float* ib = &c1[ic * 242 + y * 16 + 2 * ox0];
        float v[8];
        #pragma unroll
        for (int i = 0; i < 4; ++i) { float2 t2 = *(const float2*)(ib + 2 * i); v[2*i] = t2.x; v[2*i+1] = t2.y; }
        float w_[4][4];
        #pragma unroll
        for (int kx = 0; kx < 4; ++kx)
          *(float4*)&w_[kx][0] = *(const float4*)(w2T + (ic * 16 + ky * 4 + kx) * 64 + ocg * 4);
        #pragma unroll
        for (int o = 0; o < 4; ++o)
          #pragma unroll
          for (int p = 0; p < 3; ++p)
            acc[o][p] += w_[0][o] * v[2*p] + w_[1][o] * v[2*p+1] + w_[2][o] * v[2*p+2] + w_[3][o] * v[2*p+3];
      }
    }
    __syncthreads();
    #pragma unroll
    for (int o = 0; o < 4; ++o)
      #pragma unroll
      for (int p = 0; p < 3; ++p)
        buf[(ocg * 4 + o) * 38 + row * 6 + ox0 + p] = fmaxf(acc[o][p], 0.0f);
  }
  __syncthreads();
  {
    const int oc = tid & 63;
    const int kc = tid >> 6;
    const int k0 = (kc * 256) / 3, k1 = ((kc + 1) * 256) / 3;
    float acc[4] = {0.f, 0.f, 0.f, 0.f};
    for (int it = k0; it < k1; ++it) {
      const int ic = it >> 2;
      const int ky = it & 3;
      float v[2][6];
      #pragma unroll
      for (int oy = 0; oy < 2; ++oy) {
        const float* ib = &buf[ic * 38 + (2 * oy + ky) * 6];
        #pragma unroll
        for (int i = 0; i < 3; ++i) { float2 t2 = *(const float2*)(ib + 2 * i); v[oy][2*i] = t2.x; v[oy][2*i+1] = t2.y; }
      }
      float w_[4];
      #pragma unroll
      for (int kx = 0; kx < 4; ++kx) w_[kx] = w3T[(ic * 16 + ky * 4 + kx) * 64 + oc];
      #pragma unroll
      for (int p = 0; p < 4; ++p) {
        const int oy = p >> 1, ox = p & 1;
        acc[p] += w_[0] * v[oy][2*ox] + w_[1] * v[oy][2*ox+1] + w_[2] * v[oy][2*ox+2] + w_[3] * v[oy][2*ox+3];
      }
    }
    #pragma unroll
    for (int p = 0; p < 4; ++p) c1[kc * 260 + p * 64 + oc] = acc[p];
  }
  __syncthreads();
  for (int o = tid; o < 256; o += ENT) {
    const int oc = o >> 2, p = o & 3;
    c1[1024 + o] = b3[oc] + c1[p * 64 + oc] + c1[260 + p * 64 + oc] + c1[520 + p * 64 + oc];
  }
  __syncthreads();
  {
    const int d  = tid & 63;
    const int kc = tid >> 6;
    const int k0 = (kc * 256) / 3, k1 = ((kc + 1) * 256) / 3;
    float s = 0.0f;
    for (int k = k0; k < k1; ++k) s += ewT[k * 64 + d] * c1[1024 + k];
    c1[1536 + kc * 64 + d] = s;
  }
  __syncthreads();
  if (tid < 64) {
    z_all[(size_t)bid * 64 + tid] = eb[tid] + c1[1536 + tid] + c1[1600 + tid] + c1[1664 + tid];
  }
}

// ---------------------------------------------------------------------------
// z-Gram: z_gram[b][t][n] = z_t . z_n
// ---------------------------------------------------------------------------
__global__ __launch_bounds__(256) void gram_kernel(
    const float* __restrict__ z_all, float* __restrict__ z_gram)
{
  const int b = blockIdx.x;
  const int tid = threadIdx.x;
  __shared__ float zsb[64 * 65];
  for (int i = tid; i < 4096; i += 256) {
    const int tt = i >> 6, d = i & 63;
    zsb[tt * 65 + d] = z_all[((size_t)tt * 256 + b) * 64 + d];
  }
  __syncthreads();
  const int n = tid & 63, tg = tid >> 6;
  for (int tt = tg; tt < 64; tt += 4) {
    float s = 0.0f;
    #pragma unroll
    for (int d = 0; d < 64; ++d) s += zsb[tt * 65 + d] * zsb[n * 65 + d];
    z_gram[((size_t)b * 64 + tt) * 64 + n] = s;
  }
}

// ---------------------------------------------------------------------------
// Merged scan step (64 launches). Grid 512 x 256:
//   blocks 0-255 (gates, g=bid): G(t)[b0..b0+16][jt*128..+128) = X(t-1)@WT.
//     X(t-1) from previous kernel (coherent via kernel boundary) -> NO wait.
//     jt = bid&15 -> XCD bid%8 = jt%8 -> W slice (297 KB) L2-resident.
//     After stores: release fence + tagged flag (t+1).
//   blocks 256-511 (step, b=bid-256): poll 16 producer flags (tid<16, tagged,
//     s_sleep), one acquire fence, then LSTM elementwise (C global, own row),
//     69 dots (kw -> MkT[b] col t), masked softmax (z_gram), memory read ->
//     X(t)[b]. X consumed only by NEXT kernel -> no release needed (kernel
//     boundary). Deadlock-free: producers never wait.
// ---------------------------------------------------------------------------
__global__ __launch_bounds__(256, 2) void scan_merged_kernel(
    const int t,
    const float* __restrict__ WT, const float* __restrict__ bsum,
    const float* __restrict__ z_gram,
    float* __restrict__ X, float* __restrict__ Gp,
    float* __restrict__ C, float* __restrict__ MkT,
    unsigned int* gflag, float* __restrict__ o_ptr,
    const float* __restrict__ out_w, const float* __restrict__ out_b,
    const float* __restrict__ gate_w, const float* __restrict__ gate_b,
    const float* __restrict__ key_w, const float* __restrict__ key_b,
    const float* __restrict__ conf_w, const float* __restrict__ conf_b)
{
  __shared__ __align__(16) float smem[16 * 584];
  const int tid = threadIdx.x;
  const int bid = blockIdx.x;

  if (bid < 256) {
    // ===== gates role =====
    const int bt = bid >> 4, jt = bid & 15;
    const int b0 = bt * 16;
    const int tj = tid & 31, tb = tid >> 5;          // 32 j-lanes x 8 groups
    const int j0 = jt * 128 + tj * 4;

    for (int i = tid; i < 16 * 580; i += 256) {
      const int bl = i / 580, k = i - bl * 580;
      smem[bl * 584 + k] = (k < 577) ? X[(size_t)(b0 + bl) * 577 + k] : 0.0f;
    }
    __syncthreads();

    float acc[2][4];
    #pragma unroll
    for (int i = 0; i < 2; ++i) { acc[i][0]=0.f; acc[i][1]=0.f; acc[i][2]=0.f; acc[i][3]=0.f; }
    const float* wp  = WT + j0;
    const float* x0p = smem + (tb * 2) * 584;
    const float* x1p = smem + (tb * 2 + 1) * 584;
    #pragma unroll 4
    for (int k = 0; k < 580; k += 4) {
      const float4 xa = *(const float4*)(x0p + k);
      const float4 xb = *(const float4*)(x1p + k);
      const float xav[4] = {xa.x, xa.y, xa.z, xa.w};
      const float xbv[4] = {xb.x, xb.y, xb.z, xb.w};
      #pragma unroll
      for (int kk = 0; kk < 4; ++kk) {
        const float4 w = *(const float4*)(wp + (size_t)(k + kk) * 2048);
        acc[0][0] += xav[kk] * w.x; acc[0][1] += xav[kk] * w.y;
        acc[0][2] += xav[kk] * w.z; acc[0][3] += xav[kk] * w.w;
        acc[1][0] += xbv[kk] * w.x; acc[1][1] += xbv[kk] * w.y;
        acc[1][2] += xbv[kk] * w.z; acc[1][3] += xbv[kk] * w.w;
      }
    }
    #pragma unroll
    for (int i = 0; i < 2; ++i) {
      float4 r; r.x = acc[i][0]; r.y = acc[i][1]; r.z = acc[i][2]; r.w = acc[i][3];
      *(float4*)(Gp + (size_t)(b0 + tb * 2 + i) * 2048 + j0) = r;
    }
    __syncthreads();   // all waves' stores drained before flag
    if (tid == 0) {
      __builtin_amdgcn_fence(__ATOMIC_RELEASE, "agent");
      flagStore(gflag + bid * 16, (unsigned)(t + 1));
    }
  } else {
    // ===== step role for batch b =====
    const int b = bid - 256;
    const int bt16 = (b >> 4) * 16;
    float* hs   = smem;          // 512
    float* wks  = smem + 512;    // 64
    float* psum = smem + 576;    // 256
    float* sgp  = smem + 832;
    float* kxp  = smem + 833;

    if (tid < 16) {
      while (flagLoad(gflag + (bt16 + tid) * 16) < (unsigned)(t + 1))
        __builtin_amdgcn_s_sleep(1);
    }
    if (tid < 64) __builtin_amdgcn_fence(__ATOMIC_ACQUIRE, "agent");
    __syncthreads();

    // LSTM elementwise: 2 j per thread; C in global (own row)
    {
      const float* gp = Gp + (size_t)b * 2048;
      #pragma unroll
      for (int h2 = 0; h2 < 2; ++h2) {
        const int jj = tid + h2 * 256;
        const float gi = bsum[jj]        + gp[jj];
        const float gf = bsum[512 + jj]  + gp[512 + jj];
        const float gg = bsum[1024 + jj] + gp[1024 + jj];
        const float go = bsum[1536 + jj] + gp[1536 + jj];
        const size_t cidx = (size_t)b * 512 + jj;
        const float c2 = sigm(gf) * C[cidx] + sigm(gi) * tanhf(gg);
        C[cidx] = c2;
        const float h = sigm(go) * tanhf(c2);
        hs[jj] = h;
        X[(size_t)b * 577 + 65 + jj] = h;
      }
    }
    __syncthreads();

    // 69 dots: kw -> MkT[b] col t, y -> out, g -> sgp
    {
      const int lane = tid & 63, wid = tid >> 6;
      for (int d = wid; d < 69; d += 4) {
        const float* row = (d < 64) ? (key_w + (size_t)d * 512)
                         : (d < 68) ? (out_w + (size_t)(d - 64) * 512)
                                    : gate_w;
        float a = 0.0f;
        #pragma unroll
        for (int kk = 0; kk < 8; ++kk) a += hs[lane + kk * 64] * row[lane + kk * 64];
        #pragma unroll
        for (int m = 32; m > 0; m >>= 1) a += __shfl_xor(a, m);
        if (lane == 0) {
          if (d < 64)      MkT[(size_t)b * 4096 + d * 64 + t] = a + key_b[d];
          else if (d < 68) o_ptr[(size_t)t * 1024 + b * 4 + (d - 64)] = a + out_b[d - 64];
          else             *sgp = sigm(a + gate_b[0]);
        }
      }
    }
    __syncthreads();

    if (t == 0) {
      if (tid < 65) X[(size_t)b * 577 + tid] = 0.0f;
    } else {
      if (tid < 64) {
        const int n = tid;
        const float sim = z_gram[((size_t)b * 64 + t) * 64 + n];
        const bool valid = (n < t);
        float mx = valid ? sim : -3.0e38f;
        #pragma unroll
        for (int m = 32; m > 0; m >>= 1) mx = fmaxf(mx, __shfl_xor(mx, m));
        const float p = valid ? expf(sim - mx) : 0.0f;
        float sum = p;
        #pragma unroll
        for (int m = 32; m > 0; m >>= 1) sum += __shfl_xor(sum, m);
        const float wk = p / sum;
        wks[n] = wk;
        float kc = wk * sigm(sim * conf_w[0] + conf_b[0]);
        #pragma unroll
        for (int m = 32; m > 0; m >>= 1) kc += __shfl_xor(kc, m);
        if (n == 0) *kxp = kc;
      }
      __syncthreads();
      {
        const int d = tid >> 2, q = tid & 3;
        const float* mr = MkT + (size_t)b * 4096 + d * 64 + q * 16;
        const float* wr = wks + q * 16;
        float a = 0.0f;
        #pragma unroll
        for (int i = 0; i < 4; ++i) {
          const float4 m4 = *(const float4*)(mr + 4 * i);
          const float4 w4 = *(const float4*)(wr + 4 * i);
          a += m4.x * w4.x + m4.y * w4.y + m4.z * w4.z + m4.w * w4.w;
        }
        psum[tid] = a;
      }
      __syncthreads();
      if (tid < 64) {
        X[(size_t)b * 577 + tid] = (*sgp) * (psum[tid * 4] + psum[tid * 4 + 1] + psum[tid * 4 + 2] + psum[tid * 4 + 3]);
      } else if (tid == 64) {
        X[(size_t)b * 577 + 64] = (*sgp) * (*kxp);
      }
    }
  }
}

// ---------------------------------------------------------------------------
extern "C" void kernel_launch(void* const* d_in, const int* in_sizes, int n_in,
                              void* d_out, int out_size, void* d_ws, size_t ws_size,
                              hipStream_t stream) {
  const float* images = (const float*)d_in[0];
  const float* w1     = (const float*)d_in[1];
  const float* b1     = (const float*)d_in[2];
  const float* w2     = (const float*)d_in[3];
  const float* b2     = (const float*)d_in[4];
  const float* w3     = (const float*)d_in[5];
  const float* b3     = (const float*)d_in[6];
  const float* ew     = (const float*)d_in[7];
  const float* eb     = (const float*)d_in[8];
  const float* w_ih   = (const float*)d_in[9];
  const float* w_hh   = (const float*)d_in[10];
  const float* b_ih   = (const float*)d_in[11];
  const float* b_hh   = (const float*)d_in[12];
  const float* out_w  = (const float*)d_in[13];
  const float* out_b  = (const float*)d_in[14];
  const float* gate_w = (const float*)d_in[15];
  const float* gate_b = (const float*)d_in[16];
  const float* key_w  = (const float*)d_in[17];
  const float* key_b  = (const float*)d_in[18];
  const float* conf_w = (const float*)d_in[19];
  const float* conf_b = (const float*)d_in[20];
  float* o_ptr = (float*)d_out;
  float* ws    = (float*)d_ws;

  // ws layout (floats)
  float* WT     = ws;                  // 1,187,840
  float* bsum   = ws + 1187840;        // 2,048
  float* w1T    = ws + 1189888;        // 1,536
  float* w2T    = ws + 1191424;        // 32,768
  float* w3T    = ws + 1224192;        // 65,536
  float* ewT    = ws + 1289728;        // 16,384
  float* z_all  = ws + 1306112;        // 1,048,576
  float* z_gram = ws + 2354688;        // 1,048,576
  float* X      = ws + 3403264;        // 147,712
  float* Gp     = ws + 3550976;        // 524,288
  float* C      = ws + 4075264;        // 131,072
  float* MkT    = ws + 4206336;        // 1,048,576
  unsigned int* gflag = (unsigned int*)(ws + 5254912);   // 256*16 uints
  const size_t baseF = 5259008;
  float* c1g = ws + baseF;
  const size_t availF = (ws_size / 4 > baseF) ? (ws_size / 4 - baseF) : 0;
  long chunkL = (long)(availF / 7680ull);
  int chunk = (chunkL > 16384) ? 16384 : (int)chunkL;

  hipMemsetAsync(X,     0, 147712 * sizeof(float), stream);
  hipMemsetAsync(C,     0, 131072 * sizeof(float), stream);
  hipMemsetAsync(gflag, 0, 4096 * sizeof(unsigned int), stream);

  prep_kernel<<<(PREP_N + 255) / 256, 256, 0, stream>>>(
      w_ih, w_hh, b_ih, b_hh, w1, w2, w3, ew, WT, bsum, w1T, w2T, w3T, ewT);

  if (chunk >= 2048) {
    for (int s0 = 0; s0 < 16384; s0 += chunk) {
      const int n = (16384 - s0 < chunk) ? (16384 - s0) : chunk;
      conv1_kernel<<<n, ENT, 0, stream>>>(images, w1T, b1, c1g, s0);
      enc2_kernel<<<n, ENT, 0, stream>>>(c1g, w2T, b2, w3T, b3, ewT, eb, z_all, s0);
    }
  } else {
    encoder_kernel<<<16384, ENT, 0, stream>>>(images, w1T, b1, w2T, b2, w3T, b3, ewT, eb, z_all);
  }

  gram_kernel<<<256, 256, 0, stream>>>(z_all, z_gram);

  for (int t = 0; t < 64; ++t) {
    scan_merged_kernel<<<512, 256, 0, stream>>>(
        t, WT, bsum, z_gram, X, Gp, C, MkT, gflag, o_ptr,
        out_w, out_b, gate_w, gate_b, key_w, key_b, conf_w, conf_b);
  }
}